// Round 2
// baseline (1362.076 us; speedup 1.0000x reference)
//
#include <hip/hip_runtime.h>

#define Hdim  1024
#define Tdim  2048
#define Bdim  4
#define HUdim 4096
#define Mrows (Bdim*Tdim)   // 8192
#define CHUNK 2048          // HU processed in HUdim/CHUNK slices
#define NCH   (HUdim/CHUNK) // 2

typedef __bf16 bf16;
typedef __bf16 bf16x8 __attribute__((ext_vector_type(8)));
typedef float  floatx4 __attribute__((ext_vector_type(4)));

__device__ __forceinline__ bf16 f2bf(float x) { return (bf16)x; }

// ---------------- weight transpose + f32->bf16 convert ----------------
// src [K,N] row-major f32  ->  dst [N,K] row-major bf16
__global__ __launch_bounds__(256) void wconv(const float* __restrict__ src,
                                             bf16* __restrict__ dst, int K, int N) {
  __shared__ float tile[64][65];
  const int n0 = blockIdx.x * 64, k0 = blockIdx.y * 64;
  const int tr = threadIdx.x >> 6;   // 0..3
  const int tc = threadIdx.x & 63;
#pragma unroll
  for (int j = 0; j < 16; j++) {
    int r = j * 4 + tr;
    tile[r][tc] = src[(size_t)(k0 + r) * N + n0 + tc];
  }
  __syncthreads();
#pragma unroll
  for (int j = 0; j < 16; j++) {
    int r = j * 4 + tr;
    dst[(size_t)(n0 + r) * K + k0 + tc] = f2bf(tile[tc][r]);
  }
}

// ---------------- block reduction helper (256 threads, 4 values) ----------------
__device__ __forceinline__ void block_reduce4(float v[4], float* sm) {
#pragma unroll
  for (int off = 32; off > 0; off >>= 1) {
#pragma unroll
    for (int i = 0; i < 4; i++) v[i] += __shfl_down(v[i], off, 64);
  }
  const int w = threadIdx.x >> 6;
  if ((threadIdx.x & 63) == 0) {
#pragma unroll
    for (int i = 0; i < 4; i++) sm[w * 4 + i] = v[i];
  }
  __syncthreads();
#pragma unroll
  for (int i = 0; i < 4; i++) v[i] = sm[i] + sm[4 + i] + sm[8 + i] + sm[12 + i];
  __syncthreads();
}

// ---------------- ln0 + pre-LN + shift + TM mixes ----------------
__global__ __launch_bounds__(256) void ln_mix_tm(
    const float* __restrict__ x,
    const float* __restrict__ g0, const float* __restrict__ b0,
    const float* __restrict__ g1, const float* __restrict__ b1,
    const float* __restrict__ mk, const float* __restrict__ mv, const float* __restrict__ mr,
    float* __restrict__ x0, bf16* __restrict__ xk, bf16* __restrict__ xv, bf16* __restrict__ xr) {
  __shared__ float sm[16];
  const int bid = blockIdx.x;
  const int t = bid & (Tdim - 1);
  const int tid = threadIdx.x;
  const bool havep = (t > 0);
  const float hp = havep ? 1.f : 0.f;
  const float* rowc = x + (size_t)bid * Hdim;
  const float* rowp = havep ? (rowc - Hdim) : rowc;  // always in-bounds

  float c[4], p[4];
#pragma unroll
  for (int j = 0; j < 4; j++) c[j] = rowc[tid * 4 + j];
#pragma unroll
  for (int j = 0; j < 4; j++) p[j] = rowp[tid * 4 + j] * hp;

  float red[4] = {0.f, 0.f, 0.f, 0.f};
#pragma unroll
  for (int j = 0; j < 4; j++) { red[0] += c[j]; red[1] += c[j]*c[j]; red[2] += p[j]; red[3] += p[j]*p[j]; }
  block_reduce4(red, sm);
  const float inv = 1.f / Hdim;
  float mc = red[0]*inv, vc = red[1]*inv - mc*mc;
  float mp = red[2]*inv, vp = red[3]*inv - mp*mp;
  float sc = rsqrtf(vc + 1e-5f), sp = rsqrtf(vp + 1e-5f);

  float yc[4], yp[4];
#pragma unroll
  for (int j = 0; j < 4; j++) {
    int i = tid * 4 + j;
    yc[j] = (c[j] - mc) * sc * g0[i] + b0[i];
    yp[j] = ((p[j] - mp) * sp * g0[i] + b0[i]) * hp;
    x0[(size_t)bid * Hdim + i] = yc[j];
  }

  float r2[4] = {0.f, 0.f, 0.f, 0.f};
#pragma unroll
  for (int j = 0; j < 4; j++) { r2[0] += yc[j]; r2[1] += yc[j]*yc[j]; r2[2] += yp[j]; r2[3] += yp[j]*yp[j]; }
  block_reduce4(r2, sm);
  float mc2 = r2[0]*inv, vc2 = r2[1]*inv - mc2*mc2;
  float mp2 = r2[2]*inv, vp2 = r2[3]*inv - mp2*mp2;
  float sc2 = rsqrtf(vc2 + 1e-5f), sp2 = rsqrtf(vp2 + 1e-5f);

#pragma unroll
  for (int j = 0; j < 4; j++) {
    int i = tid * 4 + j;
    float xnc = (yc[j] - mc2) * sc2 * g1[i] + b1[i];
    float xnp = ((yp[j] - mp2) * sp2 * g1[i] + b1[i]) * hp;
    size_t o = (size_t)bid * Hdim + i;
    float a;
    a = mk[i]; xk[o] = f2bf(xnc * a + xnp * (1.f - a));
    a = mv[i]; xv[o] = f2bf(xnc * a + xnp * (1.f - a));
    a = mr[i]; xr[o] = f2bf(xnc * a + xnp * (1.f - a));
  }
}

// ---------------- post-LN + shift + CM mixes ----------------
__global__ __launch_bounds__(256) void ln_mix_cm(
    const float* __restrict__ xin,
    const float* __restrict__ g, const float* __restrict__ bb,
    const float* __restrict__ mk, const float* __restrict__ mr,
    bf16* __restrict__ xk, bf16* __restrict__ xr) {
  __shared__ float sm[16];
  const int bid = blockIdx.x;
  const int t = bid & (Tdim - 1);
  const int tid = threadIdx.x;
  const bool havep = (t > 0);
  const float hp = havep ? 1.f : 0.f;
  const float* rowc = xin + (size_t)bid * Hdim;
  const float* rowp = havep ? (rowc - Hdim) : rowc;

  float c[4], p[4];
#pragma unroll
  for (int j = 0; j < 4; j++) c[j] = rowc[tid * 4 + j];
#pragma unroll
  for (int j = 0; j < 4; j++) p[j] = rowp[tid * 4 + j] * hp;

  float red[4] = {0.f, 0.f, 0.f, 0.f};
#pragma unroll
  for (int j = 0; j < 4; j++) { red[0] += c[j]; red[1] += c[j]*c[j]; red[2] += p[j]; red[3] += p[j]*p[j]; }
  block_reduce4(red, sm);
  const float inv = 1.f / Hdim;
  float mc = red[0]*inv, vc = red[1]*inv - mc*mc;
  float mp = red[2]*inv, vp = red[3]*inv - mp*mp;
  float sc = rsqrtf(vc + 1e-5f), sp = rsqrtf(vp + 1e-5f);

#pragma unroll
  for (int j = 0; j < 4; j++) {
    int i = tid * 4 + j;
    float xnc = (c[j] - mc) * sc * g[i] + bb[i];
    float xnp = ((p[j] - mp) * sp * g[i] + bb[i]) * hp;
    size_t o = (size_t)bid * Hdim + i;
    float a;
    a = mk[i]; xk[o] = f2bf(xnc * a + xnp * (1.f - a));
    a = mr[i]; xr[o] = f2bf(xnc * a + xnp * (1.f - a));
  }
}

// ---------------- WKV sequential scan (one CHUNK-wide channel slice) ----------------
// grid Bdim*(CHUNK/64), block 64. 1 thread = 1 (b, channel).
#define SCHUNK 16
__global__ __launch_bounds__(64) void wkv_scan(
    const bf16* __restrict__ Kb, const bf16* __restrict__ KVb,
    const bf16* SRb, bf16* Pb,   // SRb/Pb alias: per-element read-before-write
    const float* __restrict__ tdec, const float* __restrict__ tfst) {
  const int b = blockIdx.x >> 5;                    // CHUNK/64 == 32 blocks per batch
  const int c = ((blockIdx.x & 31) << 6) + threadIdx.x;
  const float decay = __expf(-__expf(tdec[c]));
  const float first = __expf(tfst[c]);
  size_t base = ((size_t)b * Tdim) * CHUNK + c;
  float sk = 0.f, skv = 0.f;
  for (int t0 = 0; t0 < Tdim; t0 += SCHUNK) {
    float kk[SCHUNK], vv[SCHUNK], rr[SCHUNK];
#pragma unroll
    for (int j = 0; j < SCHUNK; j++) {
      size_t idx = base + (size_t)(t0 + j) * CHUNK;
      kk[j] = (float)Kb[idx];
      vv[j] = (float)KVb[idx];
      rr[j] = (float)SRb[idx];
    }
#pragma unroll
    for (int j = 0; j < SCHUNK; j++) {
      size_t idx = base + (size_t)(t0 + j) * CHUNK;
      float wk  = fmaf(first, kk[j], sk) + 1e-8f;
      float wkv = fmaf(first, vv[j], skv);
      Pb[idx] = f2bf(rr[j] * wkv / wk);
      sk  = fmaf(decay, sk, kk[j]);
      skv = fmaf(decay, skv, vv[j]);
    }
  }
}

// ---------------- MFMA GEMM: C[.,.] = A @ Bt^T, fused epilogues ----------------
__device__ __forceinline__ void gld_lds(const bf16* g, bf16* l) {
  __builtin_amdgcn_global_load_lds(
      (const __attribute__((address_space(1))) void*)(g),
      (__attribute__((address_space(3))) void*)(l),
      16, 0, 0);
}

enum { E_EXP = 0, E_MULAUX = 1, E_SIG = 2, E_ADD1 = 3, E_SILU = 4, E_F32 = 5, E_SIGADD2 = 6 };

template <int EPI>
__global__ __launch_bounds__(256) void gemm_bt(
    const bf16* __restrict__ A, const bf16* __restrict__ Bt,
    void* Cout, const void* aux1, const void* aux2,
    int lda, int ldb, int ldc, int K) {
  __shared__ __align__(16) bf16 As[128 * 32];
  __shared__ __align__(16) bf16 Bs[128 * 32];
  const int tid = threadIdx.x;
  const int lane = tid & 63;
  const int wv = tid >> 6;
  const int wm = wv >> 1, wn = wv & 1;
  const long m0 = (long)blockIdx.y * 128;
  const long n0 = (long)blockIdx.x * 128;

  floatx4 acc[4][4];
#pragma unroll
  for (int i = 0; i < 4; i++)
#pragma unroll
    for (int j = 0; j < 4; j++) acc[i][j] = (floatx4){0.f, 0.f, 0.f, 0.f};

  // staging: wave wv covers 32 rows [wv*32, wv*32+32); lane -> (row=+lane/4, col8=lane%4)
  const int srow = wv * 32 + (lane >> 2);
  const int scol = (lane & 3) * 8;
  const bf16* gA = A + (m0 + srow) * (long)lda + scol;
  const bf16* gB = Bt + (n0 + srow) * (long)ldb + scol;
  const long skipA = 16L * lda;
  const long skipB = 16L * ldb;
  bf16* lA = As + wv * 1024;
  bf16* lB = Bs + wv * 1024;

  const bf16* fa = As + ((wm * 64) + (lane & 15)) * 32 + (lane >> 4) * 8;
  const bf16* fb = Bs + ((wn * 64) + (lane & 15)) * 32 + (lane >> 4) * 8;

  const int ksteps = K >> 5;
  for (int kt = 0; kt < ksteps; ++kt) {
    __syncthreads();
    gld_lds(gA, lA);
    gld_lds(gA + skipA, lA + 512);
    gld_lds(gB, lB);
    gld_lds(gB + skipB, lB + 512);
    gA += 32; gB += 32;
    __syncthreads();
    bf16x8 af[4], bfr[4];
#pragma unroll
    for (int i = 0; i < 4; i++) {
      af[i]  = *(const bf16x8*)(fa + i * 512);
      bfr[i] = *(const bf16x8*)(fb + i * 512);
    }
#pragma unroll
    for (int mt = 0; mt < 4; mt++)
#pragma unroll
      for (int nt = 0; nt < 4; nt++)
        acc[mt][nt] = __builtin_amdgcn_mfma_f32_16x16x32_bf16(af[mt], bfr[nt], acc[mt][nt], 0, 0, 0);
  }

  // epilogue: C/D layout col = lane&15, row = (lane>>4)*4 + i
  const int r0 = wm * 64 + ((lane >> 4) << 2);
  const int c0 = wn * 64 + (lane & 15);
#pragma unroll
  for (int mt = 0; mt < 4; mt++) {
#pragma unroll
    for (int i = 0; i < 4; i++) {
      long r = m0 + r0 + mt * 16 + i;
      long bidx = r * (long)ldc + n0 + c0;
#pragma unroll
      for (int nt = 0; nt < 4; nt++) {
        long idx = bidx + nt * 16;
        float v = acc[mt][nt][i];
        if constexpr (EPI == E_EXP) {
          ((bf16*)Cout)[idx] = f2bf(__expf(fminf(v, 60.f)));
        } else if constexpr (EPI == E_MULAUX) {
          ((bf16*)Cout)[idx] = f2bf(v * (float)(((const bf16*)aux1)[idx]));
        } else if constexpr (EPI == E_SIG) {
          ((bf16*)Cout)[idx] = f2bf(1.f / (1.f + __expf(-v)));
        } else if constexpr (EPI == E_ADD1) {
          float prev = ((const float*)aux1)[idx];   // may alias Cout (same idx)
          ((float*)Cout)[idx] = v + prev;
        } else if constexpr (EPI == E_SILU) {
          ((bf16*)Cout)[idx] = f2bf(v / (1.f + __expf(-v)));
        } else if constexpr (EPI == E_F32) {
          ((float*)Cout)[idx] = v;
        } else {  // E_SIGADD2: x1 + sigmoid(acc) + hv
          float a1 = ((const float*)aux1)[idx];
          float a2 = ((const float*)aux2)[idx];
          ((float*)Cout)[idx] = a1 + 1.f / (1.f + __expf(-v)) + a2;
        }
      }
    }
  }
}

// ---------------- launch ----------------
extern "C" void kernel_launch(void* const* d_in, const int* in_sizes, int n_in,
                              void* d_out, int out_size, void* d_ws, size_t ws_size,
                              hipStream_t stream) {
  (void)in_sizes; (void)n_in; (void)out_size; (void)ws_size;
  const float* x        = (const float*)d_in[0];
  const float* ln0_g    = (const float*)d_in[1];
  const float* ln0_b    = (const float*)d_in[2];
  const float* pre_g    = (const float*)d_in[3];
  const float* pre_b    = (const float*)d_in[4];
  const float* post_g   = (const float*)d_in[5];
  const float* post_b   = (const float*)d_in[6];
  const float* tm_decay = (const float*)d_in[7];
  const float* tm_first = (const float*)d_in[8];
  const float* tm_mix_k = (const float*)d_in[9];
  const float* tm_mix_v = (const float*)d_in[10];
  const float* tm_mix_r = (const float*)d_in[11];
  const float* tm_Wk    = (const float*)d_in[12];
  const float* tm_Wv    = (const float*)d_in[13];
  const float* tm_Wr    = (const float*)d_in[14];
  const float* tm_Wo    = (const float*)d_in[15];
  const float* cm_mix_k = (const float*)d_in[16];
  const float* cm_mix_r = (const float*)d_in[17];
  const float* cm_Wk    = (const float*)d_in[18];
  const float* cm_Wv    = (const float*)d_in[19];
  const float* cm_Wr    = (const float*)d_in[20];

  char* ws = (char*)d_ws;
  // static layout (bytes); peak 236,978,176 (226 MiB)
  bf16*  WkT  = (bf16*)(ws + 0);          // [HU,H]
  bf16*  WvT  = (bf16*)(ws + 8388608);    // [HU,H]
  bf16*  WrT  = (bf16*)(ws + 16777216);   // [HU,H]
  bf16*  WoT  = (bf16*)(ws + 25165824);   // [H,HU]
  bf16*  cWkT = (bf16*)(ws + 33554432);   // [HU,H]
  bf16*  cWvT = (bf16*)(ws + 41943040);   // [H,HU]
  bf16*  cWrT = (bf16*)(ws + 50331648);   // [H,H]
  float* xres = (float*)(ws + 52428800);  // [M,H] f32: x0 -> x1 (in-place accum)
  bf16*  xk   = (bf16*)(ws + 85983232);   // [M,H]
  bf16*  xv   = (bf16*)(ws + 102760448);
  bf16*  xr   = (bf16*)(ws + 119537664);
  bf16*  Kc   = (bf16*)(ws + 136314880);  // [M,CHUNK]
  bf16*  KVc  = (bf16*)(ws + 169869312);  // [M,CHUNK]
  bf16*  SRc  = (bf16*)(ws + 203423744);  // [M,CHUNK], P written in place
  // CM-phase aliases (regions dead by then):
  bf16*  xk2  = (bf16*)(ws + 136314880);  // over Kc
  bf16*  xr2  = (bf16*)(ws + 153092096);  // over Kc (2nd half)
  bf16*  hbuf = (bf16*)(ws + 169869312);  // [M,HU] over KVc+SRc (67,108,864 B)
  float* hv   = (float*)(ws + 85983232);  // [M,H] f32 over xk+xv

  dim3 blk(256);
  // weight transposes: grid (N/64, K/64), src [K,N] -> dst [N,K]
  wconv<<<dim3(HUdim/64, Hdim/64), blk, 0, stream>>>(tm_Wk, WkT, Hdim, HUdim);
  wconv<<<dim3(HUdim/64, Hdim/64), blk, 0, stream>>>(tm_Wv, WvT, Hdim, HUdim);
  wconv<<<dim3(HUdim/64, Hdim/64), blk, 0, stream>>>(tm_Wr, WrT, Hdim, HUdim);
  wconv<<<dim3(Hdim/64, HUdim/64), blk, 0, stream>>>(tm_Wo, WoT, HUdim, Hdim);
  wconv<<<dim3(HUdim/64, Hdim/64), blk, 0, stream>>>(cm_Wk, cWkT, Hdim, HUdim);
  wconv<<<dim3(Hdim/64, HUdim/64), blk, 0, stream>>>(cm_Wv, cWvT, HUdim, Hdim);
  wconv<<<dim3(Hdim/64, Hdim/64), blk, 0, stream>>>(cm_Wr, cWrT, Hdim, Hdim);

  ln_mix_tm<<<Mrows, blk, 0, stream>>>(x, ln0_g, ln0_b, pre_g, pre_b,
                                       tm_mix_k, tm_mix_v, tm_mix_r, xres, xk, xv, xr);

  for (int ch = 0; ch < NCH; ch++) {
    const long woff = (long)ch * CHUNK;
    gemm_bt<E_EXP>   <<<dim3(CHUNK/128, Mrows/128), blk, 0, stream>>>(
        xk, WkT + woff * Hdim, Kc, nullptr, nullptr, Hdim, Hdim, CHUNK, Hdim);
    gemm_bt<E_MULAUX><<<dim3(CHUNK/128, Mrows/128), blk, 0, stream>>>(
        xv, WvT + woff * Hdim, KVc, Kc, nullptr, Hdim, Hdim, CHUNK, Hdim);
    gemm_bt<E_SIG>   <<<dim3(CHUNK/128, Mrows/128), blk, 0, stream>>>(
        xr, WrT + woff * Hdim, SRc, nullptr, nullptr, Hdim, Hdim, CHUNK, Hdim);

    wkv_scan<<<Bdim * (CHUNK/64), dim3(64), 0, stream>>>(
        Kc, KVc, SRc, SRc, tm_decay + woff, tm_first + woff);

    // xres += P_ch @ Wo[ch*CHUNK:(ch+1)*CHUNK, :]   (chunk 0 adds onto x0)
    gemm_bt<E_ADD1>  <<<dim3(Hdim/128, Mrows/128), blk, 0, stream>>>(
        SRc, WoT + woff, xres, xres, nullptr, CHUNK, HUdim, Hdim, CHUNK);
  }

  ln_mix_cm<<<Mrows, blk, 0, stream>>>(xres, post_g, post_b, cm_mix_k, cm_mix_r, xk2, xr2);

  gemm_bt<E_SILU>  <<<dim3(HUdim/128, Mrows/128), blk, 0, stream>>>(
      xk2, cWkT, hbuf, nullptr, nullptr, Hdim, Hdim, HUdim, Hdim);
  gemm_bt<E_F32>   <<<dim3(Hdim/128, Mrows/128), blk, 0, stream>>>(
      hbuf, cWvT, hv, nullptr, nullptr, HUdim, HUdim, Hdim, HUdim);
  gemm_bt<E_SIGADD2><<<dim3(Hdim/128, Mrows/128), blk, 0, stream>>>(
      xr2, cWrT, (float*)d_out, xres, hv, Hdim, Hdim, Hdim, Hdim);
}

// Round 3
// 1064.791 us; speedup vs baseline: 1.2792x; 1.2792x over previous
//
#include <hip/hip_runtime.h>

#define Hdim  1024
#define Tdim  2048
#define Bdim  4
#define HUdim 4096
#define Mrows (Bdim*Tdim)   // 8192
#define CHUNK 2048          // HU processed in HUdim/CHUNK slices
#define NCH   (HUdim/CHUNK) // 2
#define NSEG  16            // T-segments for parallel scan
#define SEGL  (Tdim/NSEG)   // 128
#define SCHUNK 16

typedef __bf16 bf16;
typedef __bf16 bf16x8 __attribute__((ext_vector_type(8)));
typedef float  floatx4 __attribute__((ext_vector_type(4)));

__device__ __forceinline__ bf16 f2bf(float x) { return (bf16)x; }

// ---------------- weight transpose + f32->bf16 convert ----------------
// src [K,N] row-major f32  ->  dst [N,K] row-major bf16
__global__ __launch_bounds__(256) void wconv(const float* __restrict__ src,
                                             bf16* __restrict__ dst, int K, int N) {
  __shared__ float tile[64][65];
  const int n0 = blockIdx.x * 64, k0 = blockIdx.y * 64;
  const int tr = threadIdx.x >> 6;   // 0..3
  const int tc = threadIdx.x & 63;
#pragma unroll
  for (int j = 0; j < 16; j++) {
    int r = j * 4 + tr;
    tile[r][tc] = src[(size_t)(k0 + r) * N + n0 + tc];
  }
  __syncthreads();
#pragma unroll
  for (int j = 0; j < 16; j++) {
    int r = j * 4 + tr;
    dst[(size_t)(n0 + r) * K + k0 + tc] = f2bf(tile[tc][r]);
  }
}

// ---------------- block reduction helper (256 threads, 4 values) ----------------
__device__ __forceinline__ void block_reduce4(float v[4], float* sm) {
#pragma unroll
  for (int off = 32; off > 0; off >>= 1) {
#pragma unroll
    for (int i = 0; i < 4; i++) v[i] += __shfl_down(v[i], off, 64);
  }
  const int w = threadIdx.x >> 6;
  if ((threadIdx.x & 63) == 0) {
#pragma unroll
    for (int i = 0; i < 4; i++) sm[w * 4 + i] = v[i];
  }
  __syncthreads();
#pragma unroll
  for (int i = 0; i < 4; i++) v[i] = sm[i] + sm[4 + i] + sm[8 + i] + sm[12 + i];
  __syncthreads();
}

// ---------------- ln0 + pre-LN + shift + TM mixes ----------------
__global__ __launch_bounds__(256) void ln_mix_tm(
    const float* __restrict__ x,
    const float* __restrict__ g0, const float* __restrict__ b0,
    const float* __restrict__ g1, const float* __restrict__ b1,
    const float* __restrict__ mk, const float* __restrict__ mv, const float* __restrict__ mr,
    float* __restrict__ x0, bf16* __restrict__ xk, bf16* __restrict__ xv, bf16* __restrict__ xr) {
  __shared__ float sm[16];
  const int bid = blockIdx.x;
  const int t = bid & (Tdim - 1);
  const int tid = threadIdx.x;
  const bool havep = (t > 0);
  const float hp = havep ? 1.f : 0.f;
  const float* rowc = x + (size_t)bid * Hdim;
  const float* rowp = havep ? (rowc - Hdim) : rowc;  // always in-bounds

  float c[4], p[4];
#pragma unroll
  for (int j = 0; j < 4; j++) c[j] = rowc[tid * 4 + j];
#pragma unroll
  for (int j = 0; j < 4; j++) p[j] = rowp[tid * 4 + j] * hp;

  float red[4] = {0.f, 0.f, 0.f, 0.f};
#pragma unroll
  for (int j = 0; j < 4; j++) { red[0] += c[j]; red[1] += c[j]*c[j]; red[2] += p[j]; red[3] += p[j]*p[j]; }
  block_reduce4(red, sm);
  const float inv = 1.f / Hdim;
  float mc = red[0]*inv, vc = red[1]*inv - mc*mc;
  float mp = red[2]*inv, vp = red[3]*inv - mp*mp;
  float sc = rsqrtf(vc + 1e-5f), sp = rsqrtf(vp + 1e-5f);

  float yc[4], yp[4];
#pragma unroll
  for (int j = 0; j < 4; j++) {
    int i = tid * 4 + j;
    yc[j] = (c[j] - mc) * sc * g0[i] + b0[i];
    yp[j] = ((p[j] - mp) * sp * g0[i] + b0[i]) * hp;
    x0[(size_t)bid * Hdim + i] = yc[j];
  }

  float r2[4] = {0.f, 0.f, 0.f, 0.f};
#pragma unroll
  for (int j = 0; j < 4; j++) { r2[0] += yc[j]; r2[1] += yc[j]*yc[j]; r2[2] += yp[j]; r2[3] += yp[j]*yp[j]; }
  block_reduce4(r2, sm);
  float mc2 = r2[0]*inv, vc2 = r2[1]*inv - mc2*mc2;
  float mp2 = r2[2]*inv, vp2 = r2[3]*inv - mp2*mp2;
  float sc2 = rsqrtf(vc2 + 1e-5f), sp2 = rsqrtf(vp2 + 1e-5f);

#pragma unroll
  for (int j = 0; j < 4; j++) {
    int i = tid * 4 + j;
    float xnc = (yc[j] - mc2) * sc2 * g1[i] + b1[i];
    float xnp = ((yp[j] - mp2) * sp2 * g1[i] + b1[i]) * hp;
    size_t o = (size_t)bid * Hdim + i;
    float a;
    a = mk[i]; xk[o] = f2bf(xnc * a + xnp * (1.f - a));
    a = mv[i]; xv[o] = f2bf(xnc * a + xnp * (1.f - a));
    a = mr[i]; xr[o] = f2bf(xnc * a + xnp * (1.f - a));
  }
}

// ---------------- post-LN + shift + CM mixes ----------------
__global__ __launch_bounds__(256) void ln_mix_cm(
    const float* __restrict__ xin,
    const float* __restrict__ g, const float* __restrict__ bb,
    const float* __restrict__ mk, const float* __restrict__ mr,
    bf16* __restrict__ xk, bf16* __restrict__ xr) {
  __shared__ float sm[16];
  const int bid = blockIdx.x;
  const int t = bid & (Tdim - 1);
  const int tid = threadIdx.x;
  const bool havep = (t > 0);
  const float hp = havep ? 1.f : 0.f;
  const float* rowc = xin + (size_t)bid * Hdim;
  const float* rowp = havep ? (rowc - Hdim) : rowc;

  float c[4], p[4];
#pragma unroll
  for (int j = 0; j < 4; j++) c[j] = rowc[tid * 4 + j];
#pragma unroll
  for (int j = 0; j < 4; j++) p[j] = rowp[tid * 4 + j] * hp;

  float red[4] = {0.f, 0.f, 0.f, 0.f};
#pragma unroll
  for (int j = 0; j < 4; j++) { red[0] += c[j]; red[1] += c[j]*c[j]; red[2] += p[j]; red[3] += p[j]*p[j]; }
  block_reduce4(red, sm);
  const float inv = 1.f / Hdim;
  float mc = red[0]*inv, vc = red[1]*inv - mc*mc;
  float mp = red[2]*inv, vp = red[3]*inv - mp*mp;
  float sc = rsqrtf(vc + 1e-5f), sp = rsqrtf(vp + 1e-5f);

#pragma unroll
  for (int j = 0; j < 4; j++) {
    int i = tid * 4 + j;
    float xnc = (c[j] - mc) * sc * g[i] + bb[i];
    float xnp = ((p[j] - mp) * sp * g[i] + bb[i]) * hp;
    size_t o = (size_t)bid * Hdim + i;
    float a;
    a = mk[i]; xk[o] = f2bf(xnc * a + xnp * (1.f - a));
    a = mr[i]; xr[o] = f2bf(xnc * a + xnp * (1.f - a));
  }
}

// ---------------- WKV parallel scan: pass A (per-segment end states) ----------------
// grid = NSEG * Bdim * (CHUNK/64), block 64. kv = k*v computed on the fly.
__global__ __launch_bounds__(64) void wkv_part(
    const bf16* __restrict__ Kb, const bf16* __restrict__ Vb,
    float* __restrict__ stK, float* __restrict__ stKV,
    const float* __restrict__ tdec) {
  const int seg = blockIdx.x & (NSEG - 1);
  const int rest = blockIdx.x >> 4;       // b*32 + g
  const int b = rest >> 5, g = rest & 31;
  const int c = (g << 6) + threadIdx.x;
  const float decay = __expf(-__expf(tdec[c]));
  size_t base = ((size_t)b * Tdim + (size_t)seg * SEGL) * CHUNK + c;
  float sk = 0.f, skv = 0.f;
  for (int t0 = 0; t0 < SEGL; t0 += SCHUNK) {
    float kk[SCHUNK], vv[SCHUNK];
#pragma unroll
    for (int j = 0; j < SCHUNK; j++) {
      size_t idx = base + (size_t)(t0 + j) * CHUNK;
      kk[j] = (float)Kb[idx];
      vv[j] = (float)Vb[idx];
    }
#pragma unroll
    for (int j = 0; j < SCHUNK; j++) {
      float kvt = kk[j] * vv[j];
      sk  = fmaf(decay, sk, kk[j]);
      skv = fmaf(decay, skv, kvt);
    }
  }
  size_t so = ((size_t)seg * Bdim + b) * CHUNK + c;
  stK[so]  = sk;
  stKV[so] = skv;
}

// ---------------- WKV parallel scan: pass B (fold carry, emit P) ----------------
__global__ __launch_bounds__(64) void wkv_emit(
    const bf16* __restrict__ Kb, const bf16* __restrict__ Vb,
    const bf16* SRb, bf16* Pb,   // SRb/Pb alias: per-element read-before-write
    const float* __restrict__ stK, const float* __restrict__ stKV,
    const float* __restrict__ tdec, const float* __restrict__ tfst) {
  const int seg = blockIdx.x & (NSEG - 1);
  const int rest = blockIdx.x >> 4;
  const int b = rest >> 5, g = rest & 31;
  const int c = (g << 6) + threadIdx.x;
  const float ed = __expf(tdec[c]);
  const float decay = __expf(-ed);
  const float dfac  = __expf(-ed * (float)SEGL);   // decay^SEGL, exact closed form
  const float first = __expf(tfst[c]);

  // carry = sum_{j<seg} dfac^{seg-1-j} * e_j  (ascending j: carry = dfac*carry + e_j)
  float sk = 0.f, skv = 0.f;
  for (int j = 0; j < seg; j++) {
    size_t so = ((size_t)j * Bdim + b) * CHUNK + c;
    sk  = fmaf(dfac, sk, stK[so]);
    skv = fmaf(dfac, skv, stKV[so]);
  }

  size_t base = ((size_t)b * Tdim + (size_t)seg * SEGL) * CHUNK + c;
  for (int t0 = 0; t0 < SEGL; t0 += SCHUNK) {
    float kk[SCHUNK], vv[SCHUNK], rr[SCHUNK];
#pragma unroll
    for (int j = 0; j < SCHUNK; j++) {
      size_t idx = base + (size_t)(t0 + j) * CHUNK;
      kk[j] = (float)Kb[idx];
      vv[j] = (float)Vb[idx];
      rr[j] = (float)SRb[idx];
    }
#pragma unroll
    for (int j = 0; j < SCHUNK; j++) {
      size_t idx = base + (size_t)(t0 + j) * CHUNK;
      float kvt = kk[j] * vv[j];
      float wk  = fmaf(first, kk[j], sk) + 1e-8f;
      float wkv = fmaf(first, kvt, skv);
      Pb[idx] = f2bf(rr[j] * wkv * __builtin_amdgcn_rcpf(wk));
      sk  = fmaf(decay, sk, kk[j]);
      skv = fmaf(decay, skv, kvt);
    }
  }
}

// ---------------- MFMA GEMM: C[.,.] = A @ Bt^T, fused epilogues ----------------
__device__ __forceinline__ void gld_lds(const bf16* g, bf16* l) {
  __builtin_amdgcn_global_load_lds(
      (const __attribute__((address_space(1))) void*)(g),
      (__attribute__((address_space(3))) void*)(l),
      16, 0, 0);
}

enum { E_EXP = 0, E_BF16 = 1, E_SIG = 2, E_ADD1 = 3, E_SILU = 4, E_F32 = 5, E_SIGADD2 = 6 };

template <int EPI>
__global__ __launch_bounds__(256) void gemm_bt(
    const bf16* __restrict__ A, const bf16* __restrict__ Bt,
    void* Cout, const void* aux1, const void* aux2,
    int lda, int ldb, int ldc, int K) {
  __shared__ __align__(16) bf16 As[128 * 32];
  __shared__ __align__(16) bf16 Bs[128 * 32];
  const int tid = threadIdx.x;
  const int lane = tid & 63;
  const int wv = tid >> 6;
  const int wm = wv >> 1, wn = wv & 1;
  const long m0 = (long)blockIdx.y * 128;
  const long n0 = (long)blockIdx.x * 128;

  floatx4 acc[4][4];
#pragma unroll
  for (int i = 0; i < 4; i++)
#pragma unroll
    for (int j = 0; j < 4; j++) acc[i][j] = (floatx4){0.f, 0.f, 0.f, 0.f};

  // staging: wave wv covers 32 rows [wv*32, wv*32+32); lane -> (row=+lane/4, col8=lane%4)
  const int srow = wv * 32 + (lane >> 2);
  const int scol = (lane & 3) * 8;
  const bf16* gA = A + (m0 + srow) * (long)lda + scol;
  const bf16* gB = Bt + (n0 + srow) * (long)ldb + scol;
  const long skipA = 16L * lda;
  const long skipB = 16L * ldb;
  bf16* lA = As + wv * 1024;
  bf16* lB = Bs + wv * 1024;

  const bf16* fa = As + ((wm * 64) + (lane & 15)) * 32 + (lane >> 4) * 8;
  const bf16* fb = Bs + ((wn * 64) + (lane & 15)) * 32 + (lane >> 4) * 8;

  const int ksteps = K >> 5;
  for (int kt = 0; kt < ksteps; ++kt) {
    __syncthreads();
    gld_lds(gA, lA);
    gld_lds(gA + skipA, lA + 512);
    gld_lds(gB, lB);
    gld_lds(gB + skipB, lB + 512);
    gA += 32; gB += 32;
    __syncthreads();
    bf16x8 af[4], bfr[4];
#pragma unroll
    for (int i = 0; i < 4; i++) {
      af[i]  = *(const bf16x8*)(fa + i * 512);
      bfr[i] = *(const bf16x8*)(fb + i * 512);
    }
#pragma unroll
    for (int mt = 0; mt < 4; mt++)
#pragma unroll
      for (int nt = 0; nt < 4; nt++)
        acc[mt][nt] = __builtin_amdgcn_mfma_f32_16x16x32_bf16(af[mt], bfr[nt], acc[mt][nt], 0, 0, 0);
  }

  // epilogue: C/D layout col = lane&15, row = (lane>>4)*4 + i
  const int r0 = wm * 64 + ((lane >> 4) << 2);
  const int c0 = wn * 64 + (lane & 15);
#pragma unroll
  for (int mt = 0; mt < 4; mt++) {
#pragma unroll
    for (int i = 0; i < 4; i++) {
      long r = m0 + r0 + mt * 16 + i;
      long bidx = r * (long)ldc + n0 + c0;
#pragma unroll
      for (int nt = 0; nt < 4; nt++) {
        long idx = bidx + nt * 16;
        float v = acc[mt][nt][i];
        if constexpr (EPI == E_EXP) {
          ((bf16*)Cout)[idx] = f2bf(__expf(fminf(v, 60.f)));
        } else if constexpr (EPI == E_BF16) {
          ((bf16*)Cout)[idx] = f2bf(v);
        } else if constexpr (EPI == E_SIG) {
          ((bf16*)Cout)[idx] = f2bf(1.f / (1.f + __expf(-v)));
        } else if constexpr (EPI == E_ADD1) {
          float prev = ((const float*)aux1)[idx];   // may alias Cout (same idx)
          ((float*)Cout)[idx] = v + prev;
        } else if constexpr (EPI == E_SILU) {
          ((bf16*)Cout)[idx] = f2bf(v / (1.f + __expf(-v)));
        } else if constexpr (EPI == E_F32) {
          ((float*)Cout)[idx] = v;
        } else {  // E_SIGADD2: x1 + sigmoid(acc) + hv
          float a1 = ((const float*)aux1)[idx];
          float a2 = ((const float*)aux2)[idx];
          ((float*)Cout)[idx] = a1 + 1.f / (1.f + __expf(-v)) + a2;
        }
      }
    }
  }
}

// ---------------- launch ----------------
extern "C" void kernel_launch(void* const* d_in, const int* in_sizes, int n_in,
                              void* d_out, int out_size, void* d_ws, size_t ws_size,
                              hipStream_t stream) {
  (void)in_sizes; (void)n_in; (void)out_size; (void)ws_size;
  const float* x        = (const float*)d_in[0];
  const float* ln0_g    = (const float*)d_in[1];
  const float* ln0_b    = (const float*)d_in[2];
  const float* pre_g    = (const float*)d_in[3];
  const float* pre_b    = (const float*)d_in[4];
  const float* post_g   = (const float*)d_in[5];
  const float* post_b   = (const float*)d_in[6];
  const float* tm_decay = (const float*)d_in[7];
  const float* tm_first = (const float*)d_in[8];
  const float* tm_mix_k = (const float*)d_in[9];
  const float* tm_mix_v = (const float*)d_in[10];
  const float* tm_mix_r = (const float*)d_in[11];
  const float* tm_Wk    = (const float*)d_in[12];
  const float* tm_Wv    = (const float*)d_in[13];
  const float* tm_Wr    = (const float*)d_in[14];
  const float* tm_Wo    = (const float*)d_in[15];
  const float* cm_mix_k = (const float*)d_in[16];
  const float* cm_mix_r = (const float*)d_in[17];
  const float* cm_Wk    = (const float*)d_in[18];
  const float* cm_Wv    = (const float*)d_in[19];
  const float* cm_Wr    = (const float*)d_in[20];

  char* ws = (char*)d_ws;
  // static layout (bytes); peak 238,026,752 (227 MiB)
  bf16*  WkT  = (bf16*)(ws + 0);          // [HU,H]
  bf16*  WvT  = (bf16*)(ws + 8388608);    // [HU,H]
  bf16*  WrT  = (bf16*)(ws + 16777216);   // [HU,H]
  bf16*  WoT  = (bf16*)(ws + 25165824);   // [H,HU]
  bf16*  cWkT = (bf16*)(ws + 33554432);   // [HU,H]
  bf16*  cWvT = (bf16*)(ws + 41943040);   // [H,HU]
  bf16*  cWrT = (bf16*)(ws + 50331648);   // [H,H]
  float* xres = (float*)(ws + 52428800);  // [M,H] f32: x0 -> x1 (in-place accum)
  bf16*  xk   = (bf16*)(ws + 85983232);   // [M,H]
  bf16*  xv   = (bf16*)(ws + 102760448);
  bf16*  xr   = (bf16*)(ws + 119537664);
  bf16*  Kc   = (bf16*)(ws + 136314880);  // [M,CHUNK]
  bf16*  Vc   = (bf16*)(ws + 169869312);  // [M,CHUNK]
  bf16*  SRc  = (bf16*)(ws + 203423744);  // [M,CHUNK], P written in place
  float* stK  = (float*)(ws + 236978176); // [NSEG,B,CHUNK] f32 (512 KiB)
  float* stKV = (float*)(ws + 237502464); // [NSEG,B,CHUNK] f32 (512 KiB)
  // CM-phase aliases (regions dead by then):
  bf16*  xk2  = (bf16*)(ws + 136314880);  // over Kc
  bf16*  xr2  = (bf16*)(ws + 153092096);  // over Kc (2nd half)
  bf16*  hbuf = (bf16*)(ws + 169869312);  // [M,HU] over Vc+SRc (67,108,864 B)
  float* hv   = (float*)(ws + 85983232);  // [M,H] f32 over xk+xv

  dim3 blk(256);
  // weight transposes: grid (N/64, K/64), src [K,N] -> dst [N,K]
  wconv<<<dim3(HUdim/64, Hdim/64), blk, 0, stream>>>(tm_Wk, WkT, Hdim, HUdim);
  wconv<<<dim3(HUdim/64, Hdim/64), blk, 0, stream>>>(tm_Wv, WvT, Hdim, HUdim);
  wconv<<<dim3(HUdim/64, Hdim/64), blk, 0, stream>>>(tm_Wr, WrT, Hdim, HUdim);
  wconv<<<dim3(Hdim/64, HUdim/64), blk, 0, stream>>>(tm_Wo, WoT, HUdim, Hdim);
  wconv<<<dim3(HUdim/64, Hdim/64), blk, 0, stream>>>(cm_Wk, cWkT, Hdim, HUdim);
  wconv<<<dim3(Hdim/64, HUdim/64), blk, 0, stream>>>(cm_Wv, cWvT, HUdim, Hdim);
  wconv<<<dim3(Hdim/64, Hdim/64), blk, 0, stream>>>(cm_Wr, cWrT, Hdim, Hdim);

  ln_mix_tm<<<Mrows, blk, 0, stream>>>(x, ln0_g, ln0_b, pre_g, pre_b,
                                       tm_mix_k, tm_mix_v, tm_mix_r, xres, xk, xv, xr);

  const int scan_grid = NSEG * Bdim * (CHUNK / 64);   // 2048 blocks
  for (int ch = 0; ch < NCH; ch++) {
    const long woff = (long)ch * CHUNK;
    gemm_bt<E_EXP>  <<<dim3(CHUNK/128, Mrows/128), blk, 0, stream>>>(
        xk, WkT + woff * Hdim, Kc, nullptr, nullptr, Hdim, Hdim, CHUNK, Hdim);
    gemm_bt<E_BF16> <<<dim3(CHUNK/128, Mrows/128), blk, 0, stream>>>(
        xv, WvT + woff * Hdim, Vc, nullptr, nullptr, Hdim, Hdim, CHUNK, Hdim);
    gemm_bt<E_SIG>  <<<dim3(CHUNK/128, Mrows/128), blk, 0, stream>>>(
        xr, WrT + woff * Hdim, SRc, nullptr, nullptr, Hdim, Hdim, CHUNK, Hdim);

    wkv_part<<<scan_grid, dim3(64), 0, stream>>>(
        Kc, Vc, stK, stKV, tm_decay + woff);
    wkv_emit<<<scan_grid, dim3(64), 0, stream>>>(
        Kc, Vc, SRc, SRc, stK, stKV, tm_decay + woff, tm_first + woff);

    // xres += P_ch @ Wo[ch*CHUNK:(ch+1)*CHUNK, :]   (chunk 0 adds onto x0)
    gemm_bt<E_ADD1> <<<dim3(Hdim/128, Mrows/128), blk, 0, stream>>>(
        SRc, WoT + woff, xres, xres, nullptr, CHUNK, HUdim, Hdim, CHUNK);
  }

  ln_mix_cm<<<Mrows, blk, 0, stream>>>(xres, post_g, post_b, cm_mix_k, cm_mix_r, xk2, xr2);

  gemm_bt<E_SILU>  <<<dim3(HUdim/128, Mrows/128), blk, 0, stream>>>(
      xk2, cWkT, hbuf, nullptr, nullptr, Hdim, Hdim, HUdim, Hdim);
  gemm_bt<E_F32>   <<<dim3(Hdim/128, Mrows/128), blk, 0, stream>>>(
      hbuf, cWvT, hv, nullptr, nullptr, HUdim, HUdim, Hdim, HUdim);
  gemm_bt<E_SIGADD2><<<dim3(Hdim/128, Mrows/128), blk, 0, stream>>>(
      xr2, cWrT, (float*)d_out, xres, hv, Hdim, Hdim, Hdim, Hdim);
}